// Round 5
// baseline (22.812 us; speedup 1.0000x reference)
//
#include <hip/hip_runtime.h>

#define NPTS   384
#define DIM    256
#define GA     4              // anchors per K1 block (register-resident frags)
#define NGRP   (NPTS/GA)      // 96 anchor groups
#define NSLC   4              // j-slices
#define JS     (NPTS/NSLC)    // 96 rows per slice
#define APB2   12             // anchors per K2 block
#define NBLK2  (NPTS/APB2)    // 32 K2 blocks
#define MAXK   64
#define MARGIN 1.0f

// K1: block (g, s) computes d[a][j] for a in [4g,4g+4), j in [96s, 96s+96).
// Anchor fragments in registers; quarter-wave dots (16 lanes/row, 4 rows/wave).
__global__ __launch_bounds__(256) void triplet_dmat(const float* __restrict__ x,
                                                    float* __restrict__ dmat,
                                                    unsigned int* __restrict__ ticket) {
    const int g    = blockIdx.x;
    const int s    = blockIdx.y;
    const int tid  = threadIdx.x;
    const int lane = tid & 63;
    const int wid  = tid >> 6;
    const int sub  = lane >> 4;
    const int l16  = lane & 15;

    if (g == 0 && s == 0 && tid == 0) *ticket = 0u;   // K2 ticket reset (visible at K2 launch)

    const int a0 = g * GA;

    // anchor fragments: fa[t][q] = x[a0+t][l16*4 + q*64 .. +4)
    float4 fa[GA][4];
    #pragma unroll
    for (int t = 0; t < GA; ++t)
        #pragma unroll
        for (int q = 0; q < 4; ++q)
            fa[t][q] = *(const float4*)(x + (size_t)(a0 + t) * DIM + l16 * 4 + q * 64);

    #pragma unroll
    for (int u = 0; u < JS / 16; ++u) {               // 6 iterations, 16 rows each
        const int r = s * JS + u * 16 + wid * 4 + sub;
        const float* xr = x + (size_t)r * DIM + l16 * 4;
        float4 rx[4];
        #pragma unroll
        for (int q = 0; q < 4; ++q) rx[q] = *(const float4*)(xr + q * 64);

        float acc[GA];
        #pragma unroll
        for (int t = 0; t < GA; ++t) {
            float a = 0.f;
            #pragma unroll
            for (int q = 0; q < 4; ++q) {
                const float d0 = rx[q].x - fa[t][q].x, d1 = rx[q].y - fa[t][q].y,
                            d2 = rx[q].z - fa[t][q].z, d3 = rx[q].w - fa[t][q].w;
                a += d0*d0 + d1*d1 + d2*d2 + d3*d3;
            }
            acc[t] = a;
        }
        #pragma unroll
        for (int t = 0; t < GA; ++t)
            #pragma unroll
            for (int m = 1; m < 16; m <<= 1) acc[t] += __shfl_xor(acc[t], m, 64);

        // lanes l16<4 of each group store d[a0+l16][r] (static-index select)
        float v = acc[0];
        v = (l16 == 1) ? acc[1] : v;
        v = (l16 == 2) ? acc[2] : v;
        v = (l16 == 3) ? acc[3] : v;
        if (l16 < GA) dmat[(size_t)(a0 + l16) * NPTS + r] = v;
    }
}

// K2: 32 blocks x 12 anchors. Per wave: 3 anchors. Ballot value-compaction of
// positive-class d's, hinge accumulation, block partial, last-block final reduce.
__global__ __launch_bounds__(256) void triplet_hinge(const float* __restrict__ dmat,
                                                     const int* __restrict__ labels,
                                                     float2* __restrict__ partial,
                                                     unsigned int* __restrict__ ticket,
                                                     float* __restrict__ out) {
    const int b    = blockIdx.x;
    const int tid  = threadIdx.x;
    const int lane = tid & 63;
    const int wid  = tid >> 6;

    __shared__ int   lab[NPTS];
    __shared__ float kd[4][MAXK];       // per-wave positive-class d values
    __shared__ float wnum[4], wcnt[4];
    __shared__ int   last_sh;

    for (int j = tid; j < NPTS; j += 256) lab[j] = labels[j];
    __syncthreads();

    float num = 0.f, cnt = 0.f;
    #pragma unroll
    for (int t = 0; t < 3; ++t) {
        const int a  = b * APB2 + wid * 3 + t;
        const int li = lab[a];

        float dr[6];
        #pragma unroll
        for (int c = 0; c < 6; ++c) dr[c] = dmat[(size_t)a * NPTS + c * 64 + lane];

        // ballot value-compaction of same-class d's into kd[wid][.]
        int base = 0;
        #pragma unroll
        for (int c = 0; c < 6; ++c) {
            const bool m = (lab[c * 64 + lane] == li);
            const unsigned long long mk = __ballot(m);
            const int pre = __popcll(mk & ((1ull << lane) - 1ull));
            const int p = base + pre;
            if (m && p < MAXK) kd[wid][p] = dr[c];
            base += __popcll(mk);       // wave-uniform
        }
        const int nk = (base > MAXK) ? MAXK : base;

        #pragma unroll
        for (int c = 0; c < 6; ++c) {
            const int j = c * 64 + lane;
            if (lab[j] != li) {
                const float bb = dr[c] - MARGIN;
                for (int t2 = 0; t2 < nk; ++t2) {
                    const float h = bb + kd[wid][t2];   // wave-uniform LDS broadcast
                    num += (h > 0.f) ? h : 0.f;
                }
                cnt += (float)nk;
            }
        }
    }

    #pragma unroll
    for (int m = 1; m < 64; m <<= 1) {
        num += __shfl_xor(num, m, 64);
        cnt += __shfl_xor(cnt, m, 64);
    }
    if (lane == 0) { wnum[wid] = num; wcnt[wid] = cnt; }
    __syncthreads();

    if (tid == 0) {
        partial[b] = make_float2(wnum[0] + wnum[1] + wnum[2] + wnum[3],
                                 wcnt[0] + wcnt[1] + wcnt[2] + wcnt[3]);
        __threadfence();                                 // release partial
        const unsigned int old = atomicAdd(ticket, 1u);  // 32 RMWs total
        last_sh = (old == NBLK2 - 1) ? 1 : 0;
    }
    __syncthreads();

    if (last_sh && tid < 64) {
        __threadfence();                                 // acquire partials
        float n = 0.f, c = 0.f;
        if (tid < NBLK2) { const float2 v = partial[tid]; n = v.x; c = v.y; }
        #pragma unroll
        for (int m = 1; m < 32; m <<= 1) {
            n += __shfl_xor(n, m, 64);
            c += __shfl_xor(c, m, 64);
        }
        if (tid == 0) out[0] = n / c;
    }
}

extern "C" void kernel_launch(void* const* d_in, const int* in_sizes, int n_in,
                              void* d_out, int out_size, void* d_ws, size_t ws_size,
                              hipStream_t stream) {
    const float* x      = (const float*)d_in[0];
    const int*   labels = (const int*)d_in[1];
    float*       out    = (float*)d_out;

    float*        dmat    = (float*)d_ws;                                   // 590 KB
    float2*       partial = (float2*)((char*)d_ws + NPTS * NPTS * sizeof(float));
    unsigned int* ticket  = (unsigned int*)(partial + NBLK2);

    dim3 g1(NGRP, NSLC);
    triplet_dmat<<<g1, 256, 0, stream>>>(x, dmat, ticket);
    triplet_hinge<<<NBLK2, 256, 0, stream>>>(dmat, labels, partial, ticket, out);
}

// Round 6
// 17.380 us; speedup vs baseline: 1.3125x; 1.3125x over previous
//
#include <hip/hip_runtime.h>

#define NPTS   384
#define DIM    256
#define NSLC   4             // j-slices per anchor
#define JS     (NPTS/NSLC)   // 96 j's per block
#define NBLK   (NPTS*NSLC)   // 1536 blocks = 6/CU, all co-resident
#define MAXK   64            // cap on same-class count (expected ~12)
#define MARGIN 1.0f

__device__ __forceinline__ float wave_red_sum(float p) {
    #pragma unroll
    for (int m = 1; m < 64; m <<= 1) p += __shfl_xor(p, m, 64);
    return p;
}

// Block (i, s): anchor i, j-slice s.
//  Phase A (concurrent):
//    wave 0:  stage labels -> ballot-compact same-class kidx (no barrier needed:
//             wave 0 staged all labels itself)
//    waves 1-3: quarter-wave dots for the 96-row slice (16 lanes/row, 4 rows/wave,
//             8 iterations; 1 shfl per row)
//  Phase B: positive-k dots, all 16 quarter-wave groups in parallel (1 iter typ.)
//  Phase C: hinge accumulation (tid<96, one j each) + block reduce -> partial.
__global__ __launch_bounds__(256) void triplet_main(const float* __restrict__ x,
                                                    const int* __restrict__ labels,
                                                    float2* __restrict__ partial) {
    const int i    = blockIdx.x;
    const int s    = blockIdx.y;
    const int tid  = threadIdx.x;
    const int lane = tid & 63;
    const int wid  = tid >> 6;
    const int sub  = lane >> 4;   // row within the 4-row group
    const int l16  = lane & 15;   // element-slice lane

    __shared__ int   lab[NPTS];
    __shared__ float dj[JS];
    __shared__ float dk[MAXK];
    __shared__ int   kidx[MAXK];
    __shared__ int   nk_sh;
    __shared__ float wnum[2], wcnt[2];

    // anchor fragment: this lane's 16-element slice of row i
    float4 bx[4];
    #pragma unroll
    for (int q = 0; q < 4; ++q)
        bx[q] = *(const float4*)(x + (size_t)i * DIM + l16 * 4 + q * 64);

    if (wid == 0) {
        // stage labels (wave 0 covers all 384 itself -> self-consistent view)
        #pragma unroll
        for (int c = 0; c < 6; ++c) lab[c * 64 + lane] = labels[c * 64 + lane];
        const int li = labels[i];
        int base = 0;
        #pragma unroll
        for (int c = 0; c < 6; ++c) {
            const bool m = (lab[c * 64 + lane] == li);
            const unsigned long long mk = __ballot(m);
            const int pre = __popcll(mk & ((1ull << lane) - 1ull));
            const int p = base + pre;
            if (m && p < MAXK) kidx[p] = c * 64 + lane;
            base += __popcll(mk);          // wave-uniform
        }
        if (lane == 0) nk_sh = (base > MAXK) ? MAXK : base;
    } else {
        // slice dots: waves 1-3 cover 12 rows/iteration, 8 iterations
        #pragma unroll 2
        for (int u = 0; u < 8; ++u) {
            const int rl = u * 12 + (wid - 1) * 4 + sub;   // 0..95
            const float* xr = x + (size_t)(s * JS + rl) * DIM + l16 * 4;
            float acc = 0.f;
            #pragma unroll
            for (int q = 0; q < 4; ++q) {
                const float4 a = *(const float4*)(xr + q * 64);
                const float d0 = a.x - bx[q].x, d1 = a.y - bx[q].y,
                            d2 = a.z - bx[q].z, d3 = a.w - bx[q].w;
                acc += d0*d0 + d1*d1 + d2*d2 + d3*d3;
            }
            #pragma unroll
            for (int m = 1; m < 16; m <<= 1) acc += __shfl_xor(acc, m, 64);
            if (l16 == 0) dj[rl] = acc;
        }
    }
    __syncthreads();

    // positive-k dots: 16 groups (4 waves x 4 subs) in parallel
    const int nk = nk_sh;
    for (int t0 = 0; t0 < nk; t0 += 16) {
        const int t = t0 + wid * 4 + sub;
        if (t < nk) {                       // whole 16-lane group branches together
            const int r = kidx[t];
            const float* xr = x + (size_t)r * DIM + l16 * 4;
            float acc = 0.f;
            #pragma unroll
            for (int q = 0; q < 4; ++q) {
                const float4 a = *(const float4*)(xr + q * 64);
                const float d0 = a.x - bx[q].x, d1 = a.y - bx[q].y,
                            d2 = a.z - bx[q].z, d3 = a.w - bx[q].w;
                acc += d0*d0 + d1*d1 + d2*d2 + d3*d3;
            }
            #pragma unroll
            for (int m = 1; m < 16; m <<= 1) acc += __shfl_xor(acc, m, 64);
            if (l16 == 0) dk[t] = acc;
        }
    }
    __syncthreads();

    // hinge: thread tid<96 owns j = s*96+tid
    const int li = lab[i];
    float num = 0.f, cnt = 0.f;
    if (tid < JS) {
        const int j = s * JS + tid;
        if (lab[j] != li) {
            const float b = dj[tid] - MARGIN;
            for (int t = 0; t < nk; ++t) {
                const float h = b + dk[t];   // wave-uniform LDS broadcast
                num += (h > 0.f) ? h : 0.f;
            }
            cnt = (float)nk;
        }
    }
    if (wid < 2) {                           // values live only in tid<96
        num = wave_red_sum(num);
        cnt = wave_red_sum(cnt);
        if (lane == 0) { wnum[wid] = num; wcnt[wid] = cnt; }
    }
    __syncthreads();
    if (tid == 0)
        partial[s * NPTS + i] = make_float2(wnum[0] + wnum[1], wcnt[0] + wcnt[1]);
}

__global__ __launch_bounds__(256) void triplet_finalize(const float2* __restrict__ partial,
                                                        float* __restrict__ out) {
    const int tid = threadIdx.x, lane = tid & 63, wid = tid >> 6;
    __shared__ float wnum[4], wcnt[4];
    float n = 0.f, c = 0.f;
    for (int p = tid; p < NBLK; p += 256) {
        const float2 v = partial[p];
        n += v.x; c += v.y;
    }
    n = wave_red_sum(n);
    c = wave_red_sum(c);
    if (lane == 0) { wnum[wid] = n; wcnt[wid] = c; }
    __syncthreads();
    if (tid == 0)
        out[0] = (wnum[0] + wnum[1] + wnum[2] + wnum[3]) /
                 (wcnt[0] + wcnt[1] + wcnt[2] + wcnt[3]);
}

extern "C" void kernel_launch(void* const* d_in, const int* in_sizes, int n_in,
                              void* d_out, int out_size, void* d_ws, size_t ws_size,
                              hipStream_t stream) {
    const float* x      = (const float*)d_in[0];
    const int*   labels = (const int*)d_in[1];
    float*       out    = (float*)d_out;

    float2* partial = (float2*)d_ws;

    dim3 grid(NPTS, NSLC);
    triplet_main<<<grid, 256, 0, stream>>>(x, labels, partial);
    triplet_finalize<<<1, 256, 0, stream>>>(partial, out);
}